// Round 1
// baseline (1191.957 us; speedup 1.0000x reference)
//
#include <hip/hip_runtime.h>

#define NL   8
#define DD   64
#define SP   72            // LDS row stride in bf16 elems (144 B = 9*16 B: keeps b128 reads aligned, breaks bank pow2)
#define HIN  8192
#define HIDN 4096

using frag8 = __attribute__((ext_vector_type(8))) short;   // 8 bf16 (4 VGPRs)
using f32x4 = __attribute__((ext_vector_type(4))) float;
using s16x4 = __attribute__((ext_vector_type(4))) short;

#define MFMA16(a, b, c) __builtin_amdgcn_mfma_f32_16x16x32_bf16((a), (b), (c), 0, 0, 0)

static __device__ __forceinline__ float bf2f(unsigned short h) {
  union { unsigned u; float f; } c; c.u = ((unsigned)h) << 16; return c.f;
}
static __device__ __forceinline__ unsigned short f2bf(float f) {
  union { float f; unsigned u; } c; c.f = f;
  unsigned u = c.u + 0x7FFFu + ((c.u >> 16) & 1u);   // RNE
  return (unsigned short)(u >> 16);
}
static __device__ __forceinline__ void split2(float v, short& hi, short& lo) {
  unsigned short h = f2bf(v);
  hi = (short)h;
  lo = (short)f2bf(v - bf2f(h));
}
// Load 8 consecutive fp32 from global, split into bf16 hi/lo fragments.
static __device__ __forceinline__ void load_frag_split(const float* __restrict__ p,
                                                       frag8& hi, frag8& lo) {
  const float4 v0 = *(const float4*)(p);
  const float4 v1 = *(const float4*)(p + 4);
  float vv[8] = {v0.x, v0.y, v0.z, v0.w, v1.x, v1.y, v1.z, v1.w};
  _Pragma("unroll")
  for (int t = 0; t < 8; ++t) {
    unsigned short h = f2bf(vv[t]);
    hi[t] = (short)h;
    lo[t] = (short)f2bf(vv[t] - bf2f(h));
  }
}

static __device__ __forceinline__ float mish_f(float x) {
  float e  = __expf(x);
  float sp = (x > 15.f) ? x : __logf(1.f + e);      // softplus, stable for huge |x|
  float em = __expf(-2.f * sp);
  float t  = (1.f - em) / (1.f + em);               // tanh(sp), sp>=0
  return x * t;
}

// ---------------------------------------------------------------------------
// Kernel 1: per-batch matrix chain  out = u - W7 x7 W6 x6 ... W0 x0
// Intermediate kept in LDS transposed (B-operand layout), split bf16 hi/lo.
// A-operand fragments (W / x rows) loaded straight from global (contiguous).
// ---------------------------------------------------------------------------

// Complex split matmul: D[mrow..mrow+16)[0..64) = A(global) * B(LDS, transposed)
#define CMM_G(gr, gi) do {                                                     \
  _Pragma("unroll") for (int c = 0; c < 4; ++c) { accr[c] = zero4; acci[c] = zero4; } \
  _Pragma("unroll") for (int kc = 0; kc < 2; ++kc) {                           \
    const int k0 = kc * 32 + quad * 8;                                         \
    const int aoff = (mrow + l16) * 64 + k0;                                   \
    frag8 arh, arl, aih, ail;                                                  \
    load_frag_split((gr) + aoff, arh, arl);                                    \
    load_frag_split((gi) + aoff, aih, ail);                                    \
    frag8 aihn = aih ^ (short)0x8000;                                          \
    frag8 ailn = ail ^ (short)0x8000;                                          \
    _Pragma("unroll") for (int c = 0; c < 4; ++c) {                            \
      const int brow = (c * 16 + l16) * SP + k0;                               \
      frag8 brh = *(const frag8*)&B_rh[brow];                                  \
      frag8 brl = *(const frag8*)&B_rl[brow];                                  \
      frag8 bih = *(const frag8*)&B_ih[brow];                                  \
      frag8 bil = *(const frag8*)&B_il[brow];                                  \
      accr[c] = MFMA16(arh,  brh, accr[c]);                                    \
      accr[c] = MFMA16(arh,  brl, accr[c]);                                    \
      accr[c] = MFMA16(arl,  brh, accr[c]);                                    \
      accr[c] = MFMA16(aihn, bih, accr[c]);                                    \
      accr[c] = MFMA16(aihn, bil, accr[c]);                                    \
      accr[c] = MFMA16(ailn, bih, accr[c]);                                    \
      acci[c] = MFMA16(arh,  bih, acci[c]);                                    \
      acci[c] = MFMA16(arh,  bil, acci[c]);                                    \
      acci[c] = MFMA16(arl,  bih, acci[c]);                                    \
      acci[c] = MFMA16(aih,  brh, acci[c]);                                    \
      acci[c] = MFMA16(aih,  brl, acci[c]);                                    \
      acci[c] = MFMA16(ail,  brh, acci[c]);                                    \
    }                                                                          \
  }                                                                            \
} while (0)

// Write acc (C-layout: row=quad*4+g, col=c*16+l16) TRANSPOSED into B buffers.
#define WRITE_BT() do {                                                        \
  _Pragma("unroll") for (int c = 0; c < 4; ++c) {                              \
    const int wrow = (c * 16 + l16) * SP + mrow + quad * 4;                    \
    s16x4 rh, rl, ih, il;                                                      \
    _Pragma("unroll") for (int g = 0; g < 4; ++g) {                            \
      short h_, l_;                                                            \
      split2(accr[c][g], h_, l_); rh[g] = h_; rl[g] = l_;                      \
      split2(acci[c][g], h_, l_); ih[g] = h_; il[g] = l_;                      \
    }                                                                          \
    *(s16x4*)&B_rh[wrow] = rh;                                                 \
    *(s16x4*)&B_rl[wrow] = rl;                                                 \
    *(s16x4*)&B_ih[wrow] = ih;                                                 \
    *(s16x4*)&B_il[wrow] = il;                                                 \
  }                                                                            \
} while (0)

__global__ __launch_bounds__(256) void chain_kernel(
    const float* __restrict__ x_r, const float* __restrict__ x_i,
    const float* __restrict__ u_r, const float* __restrict__ u_i,
    const float* __restrict__ W_r, const float* __restrict__ W_i,
    unsigned short* __restrict__ feat)
{
  __shared__ short B_rh[DD * SP];
  __shared__ short B_rl[DD * SP];
  __shared__ short B_ih[DD * SP];
  __shared__ short B_il[DD * SP];

  const int tid  = threadIdx.x;
  const int b    = blockIdx.x;
  const int lane = tid & 63;
  const int quad = lane >> 4;
  const int l16  = lane & 15;
  const int mrow = (tid >> 6) * 16;          // wave's 16 output rows
  const f32x4 zero4 = {0.f, 0.f, 0.f, 0.f};
  f32x4 accr[4], acci[4];

  // stage out0 = x[b,0], transposed + split, into B
  {
    const float* xr0 = x_r + (size_t)b * (NL * DD * DD);
    const float* xi0 = x_i + (size_t)b * (NL * DD * DD);
    for (int j = 0; j < 16; ++j) {
      const int idx = j * 256 + tid;
      const int q = idx >> 6, r = idx & 63;
      short h_, l_;
      split2(xr0[idx], h_, l_); B_rh[r * SP + q] = h_; B_rl[r * SP + q] = l_;
      split2(xi0[idx], h_, l_); B_ih[r * SP + q] = h_; B_il[r * SP + q] = l_;
    }
  }
  __syncthreads();

  for (int step = 0; step < 7; ++step) {
    const float* wr = W_r + (size_t)step * (DD * DD);
    const float* wi = W_i + (size_t)step * (DD * DD);
    CMM_G(wr, wi);                            // temp = W[step] * out
    __syncthreads();                          // all waves done reading B
    WRITE_BT();                               // B <- temp^T
    __syncthreads();
    const float* xr = x_r + ((size_t)b * NL + step + 1) * (DD * DD);
    const float* xi = x_i + ((size_t)b * NL + step + 1) * (DD * DD);
    CMM_G(xr, xi);                            // out = x[step+1] * temp
    __syncthreads();
    WRITE_BT();                               // B <- out^T
    __syncthreads();
  }
  {
    const float* wr = W_r + (size_t)7 * (DD * DD);
    const float* wi = W_i + (size_t)7 * (DD * DD);
    CMM_G(wr, wi);                            // fin = W[7] * out
  }
  // epilogue: feat[b, p*128 + r] = u_r - fin_r ; feat[b, p*128+64+r] = u_i - fin_i
  const float* ur = u_r + (size_t)b * (DD * DD);
  const float* ui = u_i + (size_t)b * (DD * DD);
  unsigned short* fb = feat + (size_t)b * HIN;
  _Pragma("unroll")
  for (int c = 0; c < 4; ++c) {
    _Pragma("unroll")
    for (int g = 0; g < 4; ++g) {
      const int p = mrow + quad * 4 + g;
      const int r = c * 16 + l16;
      fb[p * 128 + r]      = f2bf(ur[p * 64 + r] - accr[c][g]);
      fb[p * 128 + 64 + r] = f2bf(ui[p * 64 + r] - acci[c][g]);
    }
  }
}

// ---------------------------------------------------------------------------
// Kernel 2/3: out[m][n] = mish( sum_k A[m][k]*Wg[n][k] + bias[n] )  (bf16 out)
// M=512, N=4096. Block tile 64(m) x 128(n), BK=64. 256 blocks, XCD swizzle so
// the 8 m-tiles sharing an n-stripe of Wg co-reside on one XCD's L2.
// ---------------------------------------------------------------------------
__global__ __launch_bounds__(256) void gemm_mish_kernel(
    const unsigned short* __restrict__ A,   // M x K bf16
    const float* __restrict__ Wg,           // N x K fp32
    const float* __restrict__ bias,         // N
    unsigned short* __restrict__ outp,      // M x N bf16
    const int K)
{
  __shared__ short As[64 * SP];
  __shared__ short Bs[128 * SP];

  const int tid  = threadIdx.x;
  const int bx   = blockIdx.x;
  const int xcd  = bx & 7, slot = bx >> 3;
  const int n_tile = xcd * 4 + (slot >> 3); // 0..31
  const int m_tile = slot & 7;              // 0..7
  const int m0 = m_tile * 64, n0 = n_tile * 128;
  const int wv = tid >> 6, lane = tid & 63, quad = lane >> 4, l16 = lane & 15;
  const f32x4 zero4 = {0.f, 0.f, 0.f, 0.f};
  f32x4 acc[4][2];
  _Pragma("unroll")
  for (int i = 0; i < 4; ++i) { acc[i][0] = zero4; acc[i][1] = zero4; }

  const int kIters = K >> 6;
  for (int kt = 0; kt < kIters; ++kt) {
    // stage A tile (64x64 bf16): 2 x frag8 per thread
    _Pragma("unroll")
    for (int j = 0; j < 2; ++j) {
      const int e = (j * 256 + tid) * 8;
      const int row = e >> 6, col = e & 63;
      *(frag8*)&As[row * SP + col] =
          *(const frag8*)(A + (size_t)(m0 + row) * K + kt * 64 + col);
    }
    // stage B tile (128x64 fp32 -> bf16): 8 x float4 per thread
    _Pragma("unroll")
    for (int j = 0; j < 8; ++j) {
      const int e = (j * 256 + tid) * 4;
      const int row = e >> 6, col = e & 63;
      const float4 v = *(const float4*)(Wg + (size_t)(n0 + row) * K + kt * 64 + col);
      s16x4 hv;
      hv[0] = (short)f2bf(v.x); hv[1] = (short)f2bf(v.y);
      hv[2] = (short)f2bf(v.z); hv[3] = (short)f2bf(v.w);
      *(s16x4*)&Bs[row * SP + col] = hv;
    }
    __syncthreads();
    _Pragma("unroll")
    for (int kc = 0; kc < 2; ++kc) {
      const int k0 = kc * 32 + quad * 8;
      frag8 af0 = *(const frag8*)&As[(l16) * SP + k0];
      frag8 af1 = *(const frag8*)&As[(16 + l16) * SP + k0];
      frag8 af2 = *(const frag8*)&As[(32 + l16) * SP + k0];
      frag8 af3 = *(const frag8*)&As[(48 + l16) * SP + k0];
      _Pragma("unroll")
      for (int j = 0; j < 2; ++j) {
        frag8 bf_ = *(const frag8*)&Bs[((wv * 2 + j) * 16 + l16) * SP + k0];
        acc[0][j] = MFMA16(af0, bf_, acc[0][j]);
        acc[1][j] = MFMA16(af1, bf_, acc[1][j]);
        acc[2][j] = MFMA16(af2, bf_, acc[2][j]);
        acc[3][j] = MFMA16(af3, bf_, acc[3][j]);
      }
    }
    __syncthreads();
  }
  _Pragma("unroll")
  for (int j = 0; j < 2; ++j) {
    const int n = n0 + (wv * 2 + j) * 16 + l16;
    const float bv = bias[n];
    _Pragma("unroll")
    for (int i = 0; i < 4; ++i) {
      _Pragma("unroll")
      for (int g = 0; g < 4; ++g) {
        const int m = m0 + i * 16 + quad * 4 + g;
        outp[(size_t)m * HIDN + n] = f2bf(mish_f(acc[i][j][g] + bv));
      }
    }
  }
}

// ---------------------------------------------------------------------------
// Kernel 4: out[b] = sum_k h2[b][k]*w3[k] + b3   (one wave per row)
// ---------------------------------------------------------------------------
__global__ __launch_bounds__(256) void gemv_kernel(
    const unsigned short* __restrict__ h2,
    const float* __restrict__ w3,
    const float* __restrict__ b3,
    float* __restrict__ outp)
{
  const int gw   = (int)((blockIdx.x * 256 + threadIdx.x) >> 6);  // row 0..511
  const int lane = threadIdx.x & 63;
  const unsigned short* hp = h2 + (size_t)gw * HIDN;
  float s = 0.f;
  for (int j = 0; j < 16; ++j) {
    const int k = j * 256 + lane * 4;
    const s16x4 h = *(const s16x4*)(hp + k);
    const float4 w = *(const float4*)(w3 + k);
    s += bf2f((unsigned short)h[0]) * w.x + bf2f((unsigned short)h[1]) * w.y
       + bf2f((unsigned short)h[2]) * w.z + bf2f((unsigned short)h[3]) * w.w;
  }
  _Pragma("unroll")
  for (int off = 32; off > 0; off >>= 1) s += __shfl_down(s, off, 64);
  if (lane == 0) outp[gw] = s + b3[0];
}

extern "C" void kernel_launch(void* const* d_in, const int* in_sizes, int n_in,
                              void* d_out, int out_size, void* d_ws, size_t ws_size,
                              hipStream_t stream) {
  const float* x_r = (const float*)d_in[0];
  const float* x_i = (const float*)d_in[1];
  const float* u_r = (const float*)d_in[2];
  const float* u_i = (const float*)d_in[3];
  const float* W_r = (const float*)d_in[4];
  const float* W_i = (const float*)d_in[5];
  const float* w1  = (const float*)d_in[6];
  const float* b1  = (const float*)d_in[7];
  const float* w2  = (const float*)d_in[8];
  const float* b2  = (const float*)d_in[9];
  const float* w3  = (const float*)d_in[10];
  const float* b3  = (const float*)d_in[11];
  float* out = (float*)d_out;

  unsigned short* feat = (unsigned short*)d_ws;            // 512*8192 bf16 = 8 MB
  unsigned short* h1   = feat + (size_t)512 * HIN;         // 512*4096 bf16 = 4 MB
  unsigned short* h2   = h1 + (size_t)512 * HIDN;          // 4 MB

  chain_kernel<<<512, 256, 0, stream>>>(x_r, x_i, u_r, u_i, W_r, W_i, feat);
  gemm_mish_kernel<<<256, 256, 0, stream>>>(feat, w1, b1, h1, HIN);
  gemm_mish_kernel<<<256, 256, 0, stream>>>(h1, w2, b2, h2, HIDN);
  gemv_kernel<<<128, 256, 0, stream>>>(h2, w3, b3, out);
}

// Round 2
// 475.231 us; speedup vs baseline: 2.5082x; 2.5082x over previous
//
#include <hip/hip_runtime.h>

#define NL   8
#define DD   64
#define SP   72            // LDS row stride (chain kernel only)
#define HIN  8192
#define HIDN 4096
#define MM   512

using frag8 = __attribute__((ext_vector_type(8))) short;   // 8 bf16 (4 VGPRs)
using f32x4 = __attribute__((ext_vector_type(4))) float;
using s16x4 = __attribute__((ext_vector_type(4))) short;

#define MFMA16(a, b, c) __builtin_amdgcn_mfma_f32_16x16x32_bf16((a), (b), (c), 0, 0, 0)

// global -> LDS direct DMA, 16 B per lane. LDS dest = wave-uniform base + lane*16.
#define GLL16(g, l)                                                            \
  __builtin_amdgcn_global_load_lds(                                            \
      (const __attribute__((address_space(1))) void*)(g),                      \
      (__attribute__((address_space(3))) void*)(l), 16, 0, 0)

static __device__ __forceinline__ float bf2f(unsigned short h) {
  union { unsigned u; float f; } c; c.u = ((unsigned)h) << 16; return c.f;
}
static __device__ __forceinline__ unsigned short f2bf(float f) {
  union { float f; unsigned u; } c; c.f = f;
  unsigned u = c.u + 0x7FFFu + ((c.u >> 16) & 1u);   // RNE
  return (unsigned short)(u >> 16);
}
static __device__ __forceinline__ void split2(float v, short& hi, short& lo) {
  unsigned short h = f2bf(v);
  hi = (short)h;
  lo = (short)f2bf(v - bf2f(h));
}
static __device__ __forceinline__ void load_frag_split(const float* __restrict__ p,
                                                       frag8& hi, frag8& lo) {
  const float4 v0 = *(const float4*)(p);
  const float4 v1 = *(const float4*)(p + 4);
  float vv[8] = {v0.x, v0.y, v0.z, v0.w, v1.x, v1.y, v1.z, v1.w};
  _Pragma("unroll")
  for (int t = 0; t < 8; ++t) {
    unsigned short h = f2bf(vv[t]);
    hi[t] = (short)h;
    lo[t] = (short)f2bf(vv[t] - bf2f(h));
  }
}

static __device__ __forceinline__ float mish_f(float x) {
  float e  = __expf(x);
  float sp = (x > 15.f) ? x : __logf(1.f + e);      // softplus, stable for huge |x|
  float em = __expf(-2.f * sp);
  float t  = (1.f - em) / (1.f + em);               // tanh(sp), sp>=0
  return x * t;
}

// pack 8 fp32 -> 8 bf16 (RTZ truncation) via v_perm_b32, 1 instr / 2 elems
static __device__ __forceinline__ frag8 pack8(f32x4 a, f32x4 b) {
  union { frag8 f; unsigned u[4]; } r;
  r.u[0] = __builtin_amdgcn_perm(__float_as_uint(a[1]), __float_as_uint(a[0]), 0x07060302u);
  r.u[1] = __builtin_amdgcn_perm(__float_as_uint(a[3]), __float_as_uint(a[2]), 0x07060302u);
  r.u[2] = __builtin_amdgcn_perm(__float_as_uint(b[1]), __float_as_uint(b[0]), 0x07060302u);
  r.u[3] = __builtin_amdgcn_perm(__float_as_uint(b[3]), __float_as_uint(b[2]), 0x07060302u);
  return r.f;
}

// ---------------------------------------------------------------------------
// Kernel 1: per-batch matrix chain  out = u - W7 x7 W6 x6 ... W0 x0
// (unchanged from round 1 — ~25 us, not the bottleneck)
// ---------------------------------------------------------------------------
#define CMM_G(gr, gi) do {                                                     \
  _Pragma("unroll") for (int c = 0; c < 4; ++c) { accr[c] = zero4; acci[c] = zero4; } \
  _Pragma("unroll") for (int kc = 0; kc < 2; ++kc) {                           \
    const int k0 = kc * 32 + quad * 8;                                         \
    const int aoff = (mrow + l16) * 64 + k0;                                   \
    frag8 arh, arl, aih, ail;                                                  \
    load_frag_split((gr) + aoff, arh, arl);                                    \
    load_frag_split((gi) + aoff, aih, ail);                                    \
    frag8 aihn = aih ^ (short)0x8000;                                          \
    frag8 ailn = ail ^ (short)0x8000;                                          \
    _Pragma("unroll") for (int c = 0; c < 4; ++c) {                            \
      const int brow = (c * 16 + l16) * SP + k0;                               \
      frag8 brh = *(const frag8*)&B_rh[brow];                                  \
      frag8 brl = *(const frag8*)&B_rl[brow];                                  \
      frag8 bih = *(const frag8*)&B_ih[brow];                                  \
      frag8 bil = *(const frag8*)&B_il[brow];                                  \
      accr[c] = MFMA16(arh,  brh, accr[c]);                                    \
      accr[c] = MFMA16(arh,  brl, accr[c]);                                    \
      accr[c] = MFMA16(arl,  brh, accr[c]);                                    \
      accr[c] = MFMA16(aihn, bih, accr[c]);                                    \
      accr[c] = MFMA16(aihn, bil, accr[c]);                                    \
      accr[c] = MFMA16(ailn, bih, accr[c]);                                    \
      acci[c] = MFMA16(arh,  bih, acci[c]);                                    \
      acci[c] = MFMA16(arh,  bil, acci[c]);                                    \
      acci[c] = MFMA16(arl,  bih, acci[c]);                                    \
      acci[c] = MFMA16(aih,  brh, acci[c]);                                    \
      acci[c] = MFMA16(aih,  brl, acci[c]);                                    \
      acci[c] = MFMA16(ail,  brh, acci[c]);                                    \
    }                                                                          \
  }                                                                            \
} while (0)

#define WRITE_BT() do {                                                        \
  _Pragma("unroll") for (int c = 0; c < 4; ++c) {                              \
    const int wrow = (c * 16 + l16) * SP + mrow + quad * 4;                    \
    s16x4 rh, rl, ih, il;                                                      \
    _Pragma("unroll") for (int g = 0; g < 4; ++g) {                            \
      short h_, l_;                                                            \
      split2(accr[c][g], h_, l_); rh[g] = h_; rl[g] = l_;                      \
      split2(acci[c][g], h_, l_); ih[g] = h_; il[g] = l_;                      \
    }                                                                          \
    *(s16x4*)&B_rh[wrow] = rh;                                                 \
    *(s16x4*)&B_rl[wrow] = rl;                                                 \
    *(s16x4*)&B_ih[wrow] = ih;                                                 \
    *(s16x4*)&B_il[wrow] = il;                                                 \
  }                                                                            \
} while (0)

__global__ __launch_bounds__(256) void chain_kernel(
    const float* __restrict__ x_r, const float* __restrict__ x_i,
    const float* __restrict__ u_r, const float* __restrict__ u_i,
    const float* __restrict__ W_r, const float* __restrict__ W_i,
    unsigned short* __restrict__ feat)
{
  __shared__ short B_rh[DD * SP];
  __shared__ short B_rl[DD * SP];
  __shared__ short B_ih[DD * SP];
  __shared__ short B_il[DD * SP];

  const int tid  = threadIdx.x;
  const int b    = blockIdx.x;
  const int lane = tid & 63;
  const int quad = lane >> 4;
  const int l16  = lane & 15;
  const int mrow = (tid >> 6) * 16;
  const f32x4 zero4 = {0.f, 0.f, 0.f, 0.f};
  f32x4 accr[4], acci[4];

  {
    const float* xr0 = x_r + (size_t)b * (NL * DD * DD);
    const float* xi0 = x_i + (size_t)b * (NL * DD * DD);
    for (int j = 0; j < 16; ++j) {
      const int idx = j * 256 + tid;
      const int q = idx >> 6, r = idx & 63;
      short h_, l_;
      split2(xr0[idx], h_, l_); B_rh[r * SP + q] = h_; B_rl[r * SP + q] = l_;
      split2(xi0[idx], h_, l_); B_ih[r * SP + q] = h_; B_il[r * SP + q] = l_;
    }
  }
  __syncthreads();

  for (int step = 0; step < 7; ++step) {
    const float* wr = W_r + (size_t)step * (DD * DD);
    const float* wi = W_i + (size_t)step * (DD * DD);
    CMM_G(wr, wi);
    __syncthreads();
    WRITE_BT();
    __syncthreads();
    const float* xr = x_r + ((size_t)b * NL + step + 1) * (DD * DD);
    const float* xi = x_i + ((size_t)b * NL + step + 1) * (DD * DD);
    CMM_G(xr, xi);
    __syncthreads();
    WRITE_BT();
    __syncthreads();
  }
  {
    const float* wr = W_r + (size_t)7 * (DD * DD);
    const float* wi = W_i + (size_t)7 * (DD * DD);
    CMM_G(wr, wi);
  }
  const float* ur = u_r + (size_t)b * (DD * DD);
  const float* ui = u_i + (size_t)b * (DD * DD);
  unsigned short* fb = feat + (size_t)b * HIN;
  _Pragma("unroll")
  for (int c = 0; c < 4; ++c) {
    _Pragma("unroll")
    for (int g = 0; g < 4; ++g) {
      const int p = mrow + quad * 4 + g;
      const int r = c * 16 + l16;
      fb[p * 128 + r]      = f2bf(ur[p * 64 + r] - accr[c][g]);
      fb[p * 128 + 64 + r] = f2bf(ui[p * 64 + r] - acci[c][g]);
    }
  }
}

// ---------------------------------------------------------------------------
// Split-K GEMM: part[s][m][n] = sum_{k in split s} A[m][k] * Wg[n][k]
// A: M x K bf16 (row-major), Wg: N x K fp32 (row-major), N = 4096, M = 512.
// Tile 128(m) x 128(n), BK = 64, 4 waves (2x2). A staged bf16 via
// global_load_lds; Wg staged fp32 via global_load_lds, converted to bf16 at
// fragment read with v_perm (RTZ). XOR swizzle => conflict-free LDS reads.
// Grid: 128*S blocks, XCD-grouped so blocks sharing a Wg stripe co-reside.
// ---------------------------------------------------------------------------
__global__ __launch_bounds__(256, 2) void gemm_splitk_kernel(
    const unsigned short* __restrict__ A,
    const float* __restrict__ Wg,
    float* __restrict__ part,
    const int K, const int S)
{
  __shared__ __align__(16) short As[128 * 64];   // 16 KB, idx = r*64 + (c ^ ((r&7)*8))
  __shared__ __align__(16) float Bs[128 * 64];   // 32 KB, idx = r*64 + 4*((c>>2) ^ (r&7)) + (c&3)

  const int tid = threadIdx.x;
  const int bx  = blockIdx.x;
  // decode: xcd = bx&7; j = bx>>3 = m + 4*(s + S*n_sub)  (m fastest => same-B blocks adjacent)
  const int jj     = bx >> 3;
  const int m_tile = jj & 3;
  const int t2     = jj >> 2;
  const int s      = t2 % S;
  const int n_sub  = t2 / S;
  const int n_tile = (bx & 7) * 4 + n_sub;
  const int m0 = m_tile * 128, n0 = n_tile * 128;
  const int kPer  = K / S;
  const int kBase = s * kPer;

  const int wv = tid >> 6, lane = tid & 63;
  const int quad = lane >> 4, l16 = lane & 15;
  const int wm = wv & 1, wn = wv >> 1;

  // --- staging address precompute -----------------------------------------
  // A: wave wv stages rows [32wv, 32wv+32), 4 instrs x 8 rows.
  //   lane: row_loc = lane>>3 (0..7), col = 8*((lane&7) ^ row_loc)
  const int arow_loc = lane >> 3;
  const int acol     = ((lane & 7) ^ arow_loc) * 8;
  const unsigned short* aG[4];
  short* aL[4];
  _Pragma("unroll")
  for (int t = 0; t < 4; ++t) {
    const int r = 32 * wv + 8 * t + arow_loc;
    aG[t] = A + (size_t)(m0 + r) * K + kBase + acol;
    aL[t] = &As[(32 * wv + 8 * t) * 64];
  }
  // B: wave wv stages rows [32wv, 32wv+32), 8 instrs x 4 rows.
  //   lane: row_loc = lane>>4 (0..3), col-group = (lane&15) ^ (row&7)
  const int brow_loc = lane >> 4;
  const float* bG[8];
  float* bL[8];
  _Pragma("unroll")
  for (int t = 0; t < 8; ++t) {
    const int r  = 32 * wv + 4 * t + brow_loc;
    const int cg = (lane & 15) ^ (r & 7);
    bG[t] = Wg + (size_t)(n0 + r) * K + kBase + cg * 4;
    bL[t] = &Bs[(32 * wv + 4 * t) * 64];
  }

  const f32x4 zero4 = {0.f, 0.f, 0.f, 0.f};
  f32x4 acc[4][4];
  _Pragma("unroll")
  for (int i = 0; i < 4; ++i)
    _Pragma("unroll")
    for (int j = 0; j < 4; ++j) acc[i][j] = zero4;

  const int kIters = kPer >> 6;
  for (int kt = 0; kt < kIters; ++kt) {
    __syncthreads();                       // previous iter's LDS reads done
    _Pragma("unroll")
    for (int t = 0; t < 4; ++t) { GLL16(aG[t], aL[t]); aG[t] += 64; }
    _Pragma("unroll")
    for (int t = 0; t < 8; ++t) { GLL16(bG[t], bL[t]); bG[t] += 64; }
    __syncthreads();                       // staging visible (vmcnt drained)

    _Pragma("unroll")
    for (int kc = 0; kc < 2; ++kc) {
      const int k0 = kc * 32 + quad * 8;
      frag8 af[4];
      _Pragma("unroll")
      for (int i = 0; i < 4; ++i) {
        const int r = wm * 64 + i * 16 + l16;        // r&7 == l16&7
        af[i] = *(const frag8*)&As[r * 64 + (k0 ^ ((l16 & 7) * 8))];
      }
      _Pragma("unroll")
      for (int j = 0; j < 4; ++j) {
        const int r    = wn * 64 + j * 16 + l16;
        const int base = r * 64;
        const int swz  = l16 & 7;
        const int cg0  = k0 >> 2;                    // even
        f32x4 f0 = *(const f32x4*)&Bs[base + 4 * (cg0 ^ swz)];
        f32x4 f1 = *(const f32x4*)&Bs[base + 4 * ((cg0 + 1) ^ swz)];
        frag8 bf = pack8(f0, f1);
        _Pragma("unroll")
        for (int i = 0; i < 4; ++i) acc[i][j] = MFMA16(af[i], bf, acc[i][j]);
      }
    }
  }

  // write fp32 partials: part[s][m][n]
  float* pb = part + (size_t)s * MM * HIDN;
  _Pragma("unroll")
  for (int i = 0; i < 4; ++i) {
    _Pragma("unroll")
    for (int j = 0; j < 4; ++j) {
      const int n = n0 + wn * 64 + j * 16 + l16;
      _Pragma("unroll")
      for (int g = 0; g < 4; ++g) {
        const int m = m0 + wm * 64 + i * 16 + quad * 4 + g;
        pb[(size_t)m * HIDN + n] = acc[i][j][g];
      }
    }
  }
}

// ---------------------------------------------------------------------------
// Reduce splits + bias + mish -> bf16
// ---------------------------------------------------------------------------
__global__ __launch_bounds__(256) void reduce_mish_kernel(
    const float* __restrict__ part, const float* __restrict__ bias,
    unsigned short* __restrict__ outp, const int S)
{
  const int idx4 = (blockIdx.x * 256 + threadIdx.x) * 4;   // < 512*4096
  const int n = idx4 & (HIDN - 1);
  f32x4 acc = *(const f32x4*)&part[idx4];
  for (int s = 1; s < S; ++s)
    acc += *(const f32x4*)&part[(size_t)s * MM * HIDN + idx4];
  const f32x4 bv = *(const f32x4*)&bias[n];
  s16x4 o;
  _Pragma("unroll")
  for (int g = 0; g < 4; ++g) o[g] = (short)f2bf(mish_f(acc[g] + bv[g]));
  *(s16x4*)&outp[idx4] = o;
}

// ---------------------------------------------------------------------------
// Final gemv: out[b] = sum_k h2[b][k]*w3[k] + b3
// ---------------------------------------------------------------------------
__global__ __launch_bounds__(256) void gemv_kernel(
    const unsigned short* __restrict__ h2,
    const float* __restrict__ w3,
    const float* __restrict__ b3,
    float* __restrict__ outp)
{
  const int gw   = (int)((blockIdx.x * 256 + threadIdx.x) >> 6);
  const int lane = threadIdx.x & 63;
  const unsigned short* hp = h2 + (size_t)gw * HIDN;
  float s = 0.f;
  for (int j = 0; j < 16; ++j) {
    const int k = j * 256 + lane * 4;
    const s16x4 h = *(const s16x4*)(hp + k);
    const float4 w = *(const float4*)(w3 + k);
    s += bf2f((unsigned short)h[0]) * w.x + bf2f((unsigned short)h[1]) * w.y
       + bf2f((unsigned short)h[2]) * w.z + bf2f((unsigned short)h[3]) * w.w;
  }
  _Pragma("unroll")
  for (int off = 32; off > 0; off >>= 1) s += __shfl_down(s, off, 64);
  if (lane == 0) outp[gw] = s + b3[0];
}

extern "C" void kernel_launch(void* const* d_in, const int* in_sizes, int n_in,
                              void* d_out, int out_size, void* d_ws, size_t ws_size,
                              hipStream_t stream) {
  const float* x_r = (const float*)d_in[0];
  const float* x_i = (const float*)d_in[1];
  const float* u_r = (const float*)d_in[2];
  const float* u_i = (const float*)d_in[3];
  const float* W_r = (const float*)d_in[4];
  const float* W_i = (const float*)d_in[5];
  const float* w1  = (const float*)d_in[6];
  const float* b1  = (const float*)d_in[7];
  const float* w2  = (const float*)d_in[8];
  const float* b2  = (const float*)d_in[9];
  const float* w3  = (const float*)d_in[10];
  const float* b3  = (const float*)d_in[11];
  float* out = (float*)d_out;

  unsigned short* feat = (unsigned short*)d_ws;             // 512*8192 bf16 = 8 MB
  unsigned short* h1   = feat + (size_t)MM * HIN;           // 4 MB
  unsigned short* h2   = h1 + (size_t)MM * HIDN;            // 4 MB
  float* part = (float*)(h2 + (size_t)MM * HIDN);           // S * 8.39 MB fp32

  const size_t baseBytes = (size_t)MM * (HIN + 2 * HIDN) * 2;
  const size_t partBytes = (size_t)MM * HIDN * 4;
  int S = 1;
  if (ws_size >= baseBytes + 4 * partBytes)      S = 4;
  else if (ws_size >= baseBytes + 2 * partBytes) S = 2;

  chain_kernel<<<512, 256, 0, stream>>>(x_r, x_i, u_r, u_i, W_r, W_i, feat);
  gemm_splitk_kernel<<<128 * S, 256, 0, stream>>>(feat, w1, part, HIN, S);
  reduce_mish_kernel<<<2048, 256, 0, stream>>>(part, b1, h1, S);
  gemm_splitk_kernel<<<128 * S, 256, 0, stream>>>(h1, w2, part, HIDN, S);
  reduce_mish_kernel<<<2048, 256, 0, stream>>>(part, b2, h2, S);
  gemv_kernel<<<128, 256, 0, stream>>>(h2, w3, b3, out);
}